// Round 1
// baseline (2409.350 us; speedup 1.0000x reference)
//
#include <hip/hip_runtime.h>
#include <hip/hip_bf16.h>

#define SDIM 1024

// ---------------- init ----------------
__global__ void init_acc_kernel(float* acc) {
    int t = threadIdx.x;
    if (t < 16) acc[t] = 0.0f;
}

// ---------------- gate: logits, softmax means, argmax ----------------
__global__ __launch_bounds__(256) void gate_kernel(
    const float* __restrict__ x, const float* __restrict__ wg,
    int* __restrict__ idx, float* __restrict__ acc, int Fdim, int accBase)
{
    __shared__ float la[8];
    int tid = threadIdx.x;
    if (tid < 8) la[tid] = 0.0f;
    __syncthreads();

    int t = blockIdx.x * 256 + tid;       // 0 .. B*S-1
    int b = t >> 10, s = t & 1023;
    float l0 = 0.f, l1 = 0.f, l2 = 0.f, l3 = 0.f;
    const float* xp = x + (size_t)b * Fdim * SDIM + s;
    for (int f = 0; f < Fdim; ++f) {
        float xv = xp[(size_t)f * SDIM];
        l0 += xv * wg[f];
        l1 += xv * wg[Fdim + f];
        l2 += xv * wg[2 * Fdim + f];
        l3 += xv * wg[3 * Fdim + f];
    }
    float m = fmaxf(fmaxf(l0, l1), fmaxf(l2, l3));
    float e0 = expf(l0 - m), e1 = expf(l1 - m), e2 = expf(l2 - m), e3 = expf(l3 - m);
    float inv = 1.0f / (e0 + e1 + e2 + e3);
    int best = 0; float bv = l0;
    if (l1 > bv) { bv = l1; best = 1; }
    if (l2 > bv) { bv = l2; best = 2; }
    if (l3 > bv) { bv = l3; best = 3; }
    idx[t] = best;
    atomicAdd(&la[0], e0 * inv);
    atomicAdd(&la[1], e1 * inv);
    atomicAdd(&la[2], e2 * inv);
    atomicAdd(&la[3], e3 * inv);
    atomicAdd(&la[4 + best], 1.0f);
    __syncthreads();
    if (tid < 8) atomicAdd(&acc[accBase + tid], la[tid]);
}

// ---------------- MoE expert matmul: y[b,d,s] = sum_f x[b,f,s] * w[e(b,s),f,d] --------
__global__ __launch_bounds__(256) void moe_mm_kernel(
    const float* __restrict__ x, const float* __restrict__ w,
    const int* __restrict__ idx, float* __restrict__ y,
    int Fdim, int Ddim)
{
    __shared__ float xs[16][33];
    __shared__ float wt[4 * 2056];   // 4 expert slices [16 f][128 d], stride-padded
    int b  = blockIdx.x >> 5;
    int s0 = (blockIdx.x & 31) * 32;
    int d0 = blockIdx.y * 128;
    int tid = threadIdx.x;
    int t = tid & 31, dg = tid >> 5;
    int e = idx[(b << 10) + s0 + t];
    float acc[16];
    #pragma unroll
    for (int j = 0; j < 16; ++j) acc[j] = 0.f;

    for (int f0 = 0; f0 < Fdim; f0 += 16) {
        #pragma unroll
        for (int l = tid; l < 512; l += 256) {
            int f = l >> 5, tt = l & 31;
            xs[f][tt] = x[((size_t)b * Fdim + f0 + f) * SDIM + s0 + tt];
        }
        for (int l = tid; l < 8192; l += 256) {
            int ee = l >> 11;
            int r  = l & 2047;          // f*128 + d
            int f  = r >> 7, d = r & 127;
            wt[ee * 2056 + r] = w[((size_t)ee * Fdim + f0 + f) * Ddim + d0 + d];
        }
        __syncthreads();
        #pragma unroll
        for (int f = 0; f < 16; ++f) {
            float xv = xs[f][t];
            const float* wp = &wt[e * 2056 + f * 128 + dg * 16];
            #pragma unroll
            for (int j = 0; j < 16; ++j) acc[j] += xv * wp[j];
        }
        __syncthreads();
    }
    #pragma unroll
    for (int j = 0; j < 16; ++j)
        y[((size_t)b * Ddim + d0 + dg * 16 + j) * SDIM + s0 + t] = acc[j];
}

// ---------------- cumsum over s + affine: y = cum/div*scale + shift ----------------
__global__ __launch_bounds__(256) void cumsum_affine_kernel(
    const float* __restrict__ h1, const float* __restrict__ divisor,
    float* __restrict__ y)
{
    int r = blockIdx.x;
    int b = r >> 10, i = r & 1023;
    const float4* dp = (const float4*)(h1 + ((size_t)b * 3072 + i) * SDIM);
    const float4* sp = (const float4*)(h1 + ((size_t)b * 3072 + 1024 + i) * SDIM);
    const float4* hp = (const float4*)(h1 + ((size_t)b * 3072 + 2048 + i) * SDIM);
    int tid = threadIdx.x;
    float4 v = dp[tid];
    float c0 = v.x, c1 = c0 + v.y, c2 = c1 + v.z, c3 = c2 + v.w;
    __shared__ float part[256];
    part[tid] = c3;
    __syncthreads();
    for (int off = 1; off < 256; off <<= 1) {
        float p = (tid >= off) ? part[tid - off] : 0.f;
        __syncthreads();
        part[tid] += p;
        __syncthreads();
    }
    float base = part[tid] - c3;
    float4 sc = sp[tid], sh = hp[tid];
    float4 dv = ((const float4*)divisor)[tid];
    float4 o;
    o.x = (base + c0) / dv.x * sc.x + sh.x;
    o.y = (base + c1) / dv.y * sc.y + sh.y;
    o.z = (base + c2) / dv.z * sc.z + sh.z;
    o.w = (base + c3) / dv.w * sc.w + sh.w;
    ((float4*)(y + ((size_t)b * 1024 + i) * SDIM))[tid] = o;
}

// ---------------- channel norm (over i=1024) + leaky relu ----------------
// mode 0: v = in[b,i,s]           (in = [B,1024,S])
// mode 1: v = in[b,i,s]*in[b,1024+i,s] + in[b,2048+i,s]   (in = [B,3072,S])
__global__ __launch_bounds__(256) void norm_kernel(
    const float* __restrict__ in, float* __restrict__ out, int mode)
{
    int blk = blockIdx.x;
    int b  = blk >> 6;
    int s0 = (blk & 63) * 16;
    int tid = threadIdx.x;
    int sg = tid & 15, grp = tid >> 4;   // 16 i-groups x 64 i each
    int s = s0 + sg;
    float sum = 0.f, ssq = 0.f;
    for (int i = grp * 64; i < grp * 64 + 64; ++i) {
        float v;
        if (mode == 0) {
            v = in[((size_t)b * 1024 + i) * SDIM + s];
        } else {
            float a  = in[((size_t)b * 3072 + i) * SDIM + s];
            float m2 = in[((size_t)b * 3072 + 1024 + i) * SDIM + s];
            float d2 = in[((size_t)b * 3072 + 2048 + i) * SDIM + s];
            v = a * m2 + d2;
        }
        sum += v; ssq += v * v;
    }
    __shared__ float rs[16][16], rq[16][16], stat[2][16];
    rs[grp][sg] = sum; rq[grp][sg] = ssq;
    __syncthreads();
    for (int h = 8; h >= 1; h >>= 1) {
        if (grp < h) {
            rs[grp][sg] += rs[grp + h][sg];
            rq[grp][sg] += rq[grp + h][sg];
        }
        __syncthreads();
    }
    if (grp == 0) {
        float S1 = rs[0][sg], S2 = rq[0][sg];
        float mean = S1 * (1.0f / 1024.0f);
        float ssc  = fmaxf(S2 - 1024.0f * mean * mean, 0.0f);
        stat[0][sg] = mean;
        stat[1][sg] = 1.0f / (sqrtf(ssc) * (1.0f / 32.0f) + 1e-5f);
    }
    __syncthreads();
    float mean = stat[0][sg], inv = stat[1][sg];
    for (int i = grp * 64; i < grp * 64 + 64; ++i) {
        float v;
        if (mode == 0) {
            v = in[((size_t)b * 1024 + i) * SDIM + s];
        } else {
            float a  = in[((size_t)b * 3072 + i) * SDIM + s];
            float m2 = in[((size_t)b * 3072 + 1024 + i) * SDIM + s];
            float d2 = in[((size_t)b * 3072 + 2048 + i) * SDIM + s];
            v = a * m2 + d2;
        }
        float o = (v - mean) * inv;
        out[((size_t)b * 1024 + i) * SDIM + s] = (o >= 0.f) ? o : 0.02f * o;
    }
}

// ---------------- causal conv1d K=3: co[b,o,s] = sum_{i,k} g[b,i,s-2+k] w1[o,i,k] ----
__global__ __launch_bounds__(256) void conv_kernel(
    const float* __restrict__ g, const float* __restrict__ w1,
    float* __restrict__ co)
{
    __shared__ float gs[16 * 35];      // 16 i x 34 s (+pad)
    __shared__ float wl[128 * 49];     // 128 o x (16 i x 3 k) (+pad)
    int b  = blockIdx.x >> 5;
    int s0 = (blockIdx.x & 31) * 32;
    int o0 = blockIdx.y * 128;
    int tid = threadIdx.x;
    int t2 = tid & 15, og = tid >> 4;  // 16 o-groups x 8 o, 2 tokens each (t2, t2+16)
    float acc[16];
    #pragma unroll
    for (int j = 0; j < 16; ++j) acc[j] = 0.f;

    for (int i0 = 0; i0 < 1024; i0 += 16) {
        for (int l = tid; l < 544; l += 256) {            // 16*34
            int i = l / 34, tt = l % 34;
            int s = s0 - 2 + tt;
            gs[i * 35 + tt] = (s >= 0) ? g[((size_t)b * 1024 + i0 + i) * SDIM + s] : 0.f;
        }
        for (int l = tid; l < 6144; l += 256) {           // 128*48
            int o = l / 48, rr = l % 48;
            wl[o * 49 + rr] = w1[((size_t)(o0 + o)) * 3072 + i0 * 3 + rr];
        }
        __syncthreads();
        #pragma unroll
        for (int i = 0; i < 16; ++i) {
            float x00 = gs[i * 35 + t2],      x01 = gs[i * 35 + t2 + 1],  x02 = gs[i * 35 + t2 + 2];
            float x10 = gs[i * 35 + t2 + 16], x11 = gs[i * 35 + t2 + 17], x12 = gs[i * 35 + t2 + 18];
            #pragma unroll
            for (int j = 0; j < 8; ++j) {
                const float* wp = &wl[(og * 8 + j) * 49 + i * 3];
                float w0v = wp[0], w1v = wp[1], w2v = wp[2];
                acc[2 * j]     += w0v * x00 + w1v * x01 + w2v * x02;
                acc[2 * j + 1] += w0v * x10 + w1v * x11 + w2v * x12;
            }
        }
        __syncthreads();
    }
    #pragma unroll
    for (int j = 0; j < 8; ++j) {
        size_t row = ((size_t)b * 3072 + o0 + og * 8 + j) * SDIM + s0;
        co[row + t2]      = acc[2 * j];
        co[row + t2 + 16] = acc[2 * j + 1];
    }
}

// ---------------- final loss ----------------
__global__ void loss_kernel(const float* __restrict__ acc, float* __restrict__ out) {
    if (threadIdx.x == 0) {
        float l = 0.f;
        for (int e = 0; e < 4; ++e)
            l += acc[e] * acc[4 + e] + acc[8 + e] * acc[12 + e];
        out[2 * 512 * 1024] = l * (1.0f / (2048.0f * 2048.0f));
    }
}

extern "C" void kernel_launch(void* const* d_in, const int* in_sizes, int n_in,
                              void* d_out, int out_size, void* d_ws, size_t ws_size,
                              hipStream_t stream) {
    const float* inp     = (const float*)d_in[0];
    const float* divisor = (const float*)d_in[1];
    const float* w0_gate = (const float*)d_in[2];
    const float* w0      = (const float*)d_in[3];
    const float* w1      = (const float*)d_in[4];
    const float* w2_gate = (const float*)d_in[5];
    const float* w2      = (const float*)d_in[6];
    float* out = (float*)d_out;

    // workspace layout (floats): h1/co [B,3072,S], g [B,1024,S], idx1, idx2, acc
    float* h1 = (float*)d_ws;             // 6291456 floats (reused as conv output)
    float* g  = h1 + 6291456;             // 2097152 floats
    int* idx1 = (int*)(g + 2097152);      // 2048
    int* idx2 = idx1 + 2048;              // 2048
    float* acc = (float*)(idx2 + 2048);   // 16

    init_acc_kernel<<<1, 16, 0, stream>>>(acc);
    // MoE 1
    gate_kernel<<<8, 256, 0, stream>>>(inp, w0_gate, idx1, acc, 512, 0);
    moe_mm_kernel<<<dim3(64, 24), 256, 0, stream>>>(inp, w0, idx1, h1, 512, 3072);
    // cumsum + affine -> g
    cumsum_affine_kernel<<<2048, 256, 0, stream>>>(h1, divisor, g);
    // norm + leaky (in-place on g)
    norm_kernel<<<128, 256, 0, stream>>>(g, g, 0);
    // conv -> h1 (reuse)
    conv_kernel<<<dim3(64, 24), 256, 0, stream>>>(g, w1, h1);
    // gated combine + norm + leaky -> g
    norm_kernel<<<128, 256, 0, stream>>>(h1, g, 1);
    // MoE 2
    gate_kernel<<<8, 256, 0, stream>>>(g, w2_gate, idx2, acc, 1024, 8);
    moe_mm_kernel<<<dim3(64, 4), 256, 0, stream>>>(g, w2, idx2, out, 1024, 512);
    loss_kernel<<<1, 64, 0, stream>>>(acc, out);
}

// Round 4
// 466.766 us; speedup vs baseline: 5.1618x; 5.1618x over previous
//
#include <hip/hip_runtime.h>
#include <hip/hip_bf16.h>

#define SDIM 1024

typedef float f32x4 __attribute__((ext_vector_type(4)));
typedef short short8 __attribute__((ext_vector_type(8)));

__device__ __forceinline__ unsigned short f2bf(float f) {
    __hip_bfloat16 h = __float2bfloat16(f);
    return *reinterpret_cast<unsigned short*>(&h);
}
__device__ __forceinline__ float bf2f(unsigned short u) {
    return __uint_as_float(((unsigned int)u) << 16);
}

// ---------------- init ----------------
__global__ void init_acc_kernel(float* acc) {
    int t = threadIdx.x;
    if (t < 16) acc[t] = 0.0f;
}

// ------- transpose + split cvt: fp32 [slice][R][C] -> bf16 hi/lo [slice][C][R] -------
__global__ __launch_bounds__(256) void transpose_cvt_split(
    const float* __restrict__ in, unsigned short* __restrict__ oh,
    unsigned short* __restrict__ ol, int R, int C, size_t sliceStride)
{
    __shared__ float t[32][33];
    int slice = blockIdx.z;
    int c0 = blockIdx.x * 32, r0 = blockIdx.y * 32;
    int tid = threadIdx.x;
    int cc = tid & 31, r8 = tid >> 5;
    const float* ip = in + slice * sliceStride;
    #pragma unroll
    for (int k = 0; k < 4; ++k) {
        int r = r8 + k * 8;
        t[r][cc] = ip[(size_t)(r0 + r) * C + c0 + cc];
    }
    __syncthreads();
    #pragma unroll
    for (int k = 0; k < 4; ++k) {
        int rr = r8 + k * 8;
        float v = t[cc][rr];
        unsigned short hi = f2bf(v);
        unsigned short lo = f2bf(v - bf2f(hi));
        size_t o = slice * sliceStride + (size_t)(c0 + rr) * R + r0 + cc;
        oh[o] = hi; ol[o] = lo;
    }
}

// ------- plain transpose + cvt (for w2, plain-bf16 MoE2) -------
__global__ __launch_bounds__(256) void transpose_cvt(
    const float* __restrict__ in, unsigned short* __restrict__ out,
    int R, int C, size_t sliceStride)
{
    __shared__ float t[32][33];
    int slice = blockIdx.z;
    int c0 = blockIdx.x * 32, r0 = blockIdx.y * 32;
    int tid = threadIdx.x;
    int cc = tid & 31, r8 = tid >> 5;
    const float* ip = in + slice * sliceStride;
    unsigned short* op = out + slice * sliceStride;
    #pragma unroll
    for (int k = 0; k < 4; ++k) {
        int r = r8 + k * 8;
        t[r][cc] = ip[(size_t)(r0 + r) * C + c0 + cc];
    }
    __syncthreads();
    #pragma unroll
    for (int k = 0; k < 4; ++k) {
        int rr = r8 + k * 8;
        op[(size_t)(c0 + rr) * R + r0 + cc] = f2bf(t[cc][rr]);
    }
}

// ------- w1 split cvt: [3072][1024][3] fp32 -> [3][3072][1024] bf16 hi/lo -------
__global__ __launch_bounds__(256) void w1cvt_split_kernel(
    const float* __restrict__ w1, unsigned short* __restrict__ wh,
    unsigned short* __restrict__ wl)
{
    int t = blockIdx.x * 256 + threadIdx.x;
    int o = t >> 10, i = t & 1023;
    const float* p = w1 + (size_t)o * 3072 + i * 3;
    #pragma unroll
    for (int k = 0; k < 3; ++k) {
        float v = p[k];
        unsigned short hi = f2bf(v);
        unsigned short lo = f2bf(v - bf2f(hi));
        size_t off = (size_t)k * 3145728 + (size_t)o * 1024 + i;
        wh[off] = hi; wl[off] = lo;
    }
}

// ---------------- gate: logits, softmax means, argmax (fp32) ----------------
__global__ __launch_bounds__(256) void gate_kernel(
    const float* __restrict__ x, const float* __restrict__ wg,
    int* __restrict__ idx, float* __restrict__ acc, int F, int accBase)
{
    __shared__ float wgs[4 * 1024];
    __shared__ float part[8][4][33];
    __shared__ float la[8];
    int tid = threadIdx.x;
    if (tid < 8) la[tid] = 0.f;
    for (int l = tid; l < 4 * F; l += 256) wgs[l] = wg[l];
    __syncthreads();
    int t0 = blockIdx.x * 32;
    int b = t0 >> 10, s0 = t0 & 1023;
    int sl = tid & 31, fg = tid >> 5;
    float l0 = 0.f, l1 = 0.f, l2 = 0.f, l3 = 0.f;
    for (int f = fg; f < F; f += 8) {
        float xv = x[((size_t)b * F + f) * SDIM + s0 + sl];
        l0 += xv * wgs[f];
        l1 += xv * wgs[F + f];
        l2 += xv * wgs[2 * F + f];
        l3 += xv * wgs[3 * F + f];
    }
    part[fg][0][sl] = l0; part[fg][1][sl] = l1;
    part[fg][2][sl] = l2; part[fg][3][sl] = l3;
    __syncthreads();
    if (fg == 0) {
        float L[4];
        #pragma unroll
        for (int e = 0; e < 4; ++e) {
            float v = 0.f;
            #pragma unroll
            for (int g2 = 0; g2 < 8; ++g2) v += part[g2][e][sl];
            L[e] = v;
        }
        float m = fmaxf(fmaxf(L[0], L[1]), fmaxf(L[2], L[3]));
        float e0 = expf(L[0] - m), e1 = expf(L[1] - m), e2 = expf(L[2] - m), e3 = expf(L[3] - m);
        float inv = 1.0f / (e0 + e1 + e2 + e3);
        int best = 0; float bv = L[0];
        if (L[1] > bv) { bv = L[1]; best = 1; }
        if (L[2] > bv) { bv = L[2]; best = 2; }
        if (L[3] > bv) { bv = L[3]; best = 3; }
        idx[t0 + sl] = best;
        atomicAdd(&la[0], e0 * inv);
        atomicAdd(&la[1], e1 * inv);
        atomicAdd(&la[2], e2 * inv);
        atomicAdd(&la[3], e3 * inv);
        atomicAdd(&la[4 + best], 1.0f);
    }
    __syncthreads();
    if (tid < 8) atomicAdd(&acc[accBase + tid], la[tid]);
}

// ---------------- MoE1 split-bf16 MFMA ----------------
// out[b,d,s] = sum_f x[b,f,s] w[e(b,s)][d][f], fp32-accurate via hi/lo bf16 pairs.
// LDS rows(64B): Xh[0,128) Xl[128,256) Wh[256,768) Wl[768,1280)
__global__ __launch_bounds__(256) void moe_split_kernel(
    const unsigned short* __restrict__ base, unsigned int XH, unsigned int XL,
    unsigned int WH, unsigned int WL,
    const int* __restrict__ idx, float* __restrict__ out,
    int Fdim, int Ddim)
{
    __shared__ unsigned short lds[1280 * 32];   // 80 KiB
    int d0 = blockIdx.x * 128;
    int t0 = blockIdx.y * 128;
    int b = t0 >> 10, s0 = t0 & 1023;
    int tid = threadIdx.x;
    int lane = tid & 63;
    int lm = lane & 15, q = lane >> 4;
    int wid = tid >> 6;
    int wm = (wid >> 1) * 64, wn = (wid & 1) * 64;

    unsigned int goH[10], goL[10];
    int ldH[10], ldL[10];
    #pragma unroll
    for (int t = 0; t < 10; ++t) {
        int cl = tid + t * 256;          // 0..2559
        int row = cl >> 2, p = cl & 3;
        int rh, rl;
        unsigned int off;
        if (row < 128) {
            off = (unsigned int)(((b << 10) + s0 + row) * Fdim + p * 8);
            goH[t] = XH + off; goL[t] = XL + off;
            rh = row; rl = row + 128;
        } else {
            int R = row - 128;           // e*128 + d_local
            int e = R >> 7, dl = R & 127;
            off = (unsigned int)((e * Ddim + d0 + dl) * Fdim + p * 8);
            goH[t] = WH + off; goL[t] = WL + off;
            rh = 256 + R; rl = 768 + R;
        }
        ldH[t] = rh * 32 + ((p ^ ((rh >> 1) & 3)) << 3);
        ldL[t] = rl * 32 + ((p ^ ((rl >> 1) & 3)) << 3);
    }

    int bofH[4], bofL[4], aofH[4][4], aofL[4][4];
    #pragma unroll
    for (int fn = 0; fn < 4; ++fn) {
        int rh = wn + fn * 16 + lm, rl = rh + 128;
        bofH[fn] = rh * 32 + ((q ^ ((rh >> 1) & 3)) << 3);
        bofL[fn] = rl * 32 + ((q ^ ((rl >> 1) & 3)) << 3);
    }
    #pragma unroll
    for (int e = 0; e < 4; ++e)
        #pragma unroll
        for (int fm = 0; fm < 4; ++fm) {
            int R = e * 128 + wm + fm * 16 + lm;
            int rh = 256 + R, rl = 768 + R;
            aofH[e][fm] = rh * 32 + ((q ^ ((rh >> 1) & 3)) << 3);
            aofL[e][fm] = rl * 32 + ((q ^ ((rl >> 1) & 3)) << 3);
        }

    int eidx[4];
    #pragma unroll
    for (int fn = 0; fn < 4; ++fn)
        eidx[fn] = idx[(b << 10) + s0 + wn + fn * 16 + lm];

    f32x4 acc[4][4];
    #pragma unroll
    for (int fm = 0; fm < 4; ++fm)
        #pragma unroll
        for (int fn = 0; fn < 4; ++fn)
            acc[fm][fn] = (f32x4){0.f, 0.f, 0.f, 0.f};

    const short8 z = {0, 0, 0, 0, 0, 0, 0, 0};

    for (int f0 = 0; f0 < Fdim; f0 += 32) {
        short8 vh[10], vl[10];
        #pragma unroll
        for (int t = 0; t < 10; ++t) vh[t] = *(const short8*)(base + goH[t] + f0);
        #pragma unroll
        for (int t = 0; t < 10; ++t) vl[t] = *(const short8*)(base + goL[t] + f0);
        __syncthreads();
        #pragma unroll
        for (int t = 0; t < 10; ++t) {
            *(short8*)(lds + ldH[t]) = vh[t];
            *(short8*)(lds + ldL[t]) = vl[t];
        }
        __syncthreads();

        short8 bh[4], bl[4];
        #pragma unroll
        for (int fn = 0; fn < 4; ++fn) {
            bh[fn] = *(const short8*)(lds + bofH[fn]);
            bl[fn] = *(const short8*)(lds + bofL[fn]);
        }
        #pragma unroll
        for (int e = 0; e < 4; ++e) {
            short8 ah[4], al[4];
            #pragma unroll
            for (int fm = 0; fm < 4; ++fm) {
                ah[fm] = *(const short8*)(lds + aofH[e][fm]);
                al[fm] = *(const short8*)(lds + aofL[e][fm]);
            }
            #pragma unroll
            for (int fn = 0; fn < 4; ++fn) {
                short8 bmH = (eidx[fn] == e) ? bh[fn] : z;
                short8 bmL = (eidx[fn] == e) ? bl[fn] : z;
                #pragma unroll
                for (int fm = 0; fm < 4; ++fm) {
                    acc[fm][fn] = __builtin_amdgcn_mfma_f32_16x16x32_bf16(ah[fm], bmH, acc[fm][fn], 0, 0, 0);
                    acc[fm][fn] = __builtin_amdgcn_mfma_f32_16x16x32_bf16(ah[fm], bmL, acc[fm][fn], 0, 0, 0);
                    acc[fm][fn] = __builtin_amdgcn_mfma_f32_16x16x32_bf16(al[fm], bmH, acc[fm][fn], 0, 0, 0);
                }
            }
        }
        __syncthreads();
    }

    #pragma unroll
    for (int fm = 0; fm < 4; ++fm)
        #pragma unroll
        for (int fn = 0; fn < 4; ++fn) {
            int d = d0 + wm + fm * 16 + q * 4;
            int s = s0 + wn + fn * 16 + lm;
            float* op = out + ((size_t)b * Ddim + d) * SDIM + s;
            #pragma unroll
            for (int r = 0; r < 4; ++r)
                op[(size_t)r * SDIM] = acc[fm][fn][r];
        }
}

// ---------------- conv1d K=3 split-bf16 MFMA ----------------
// co[b,o,s] = sum_{i,k} g[b,i,s-2+k] w1[o,i,k]; g,w1 as hi/lo bf16 pairs.
// LDS rows(64B): Gh[0,144) Gl[144,288) Wh[288,672) Wl[672,1056)
__global__ __launch_bounds__(256) void conv_split_kernel(
    const unsigned short* __restrict__ base, unsigned int GH, unsigned int GL,
    unsigned int WH, unsigned int WL, float* __restrict__ co)
{
    __shared__ unsigned short lds[1056 * 32];   // 66 KiB
    int o0 = blockIdx.x * 128;
    int t0 = blockIdx.y * 128;
    int b = t0 >> 10, s0 = t0 & 1023;
    int tid = threadIdx.x;
    int lane = tid & 63;
    int lm = lane & 15, q = lane >> 4;
    int wid = tid >> 6;
    int wm = (wid >> 1) * 64, wn = (wid & 1) * 64;

    unsigned int goH[9], goL[9];
    int ldH[9], ldL[9], act[9];
    #pragma unroll
    for (int t = 0; t < 9; ++t) {
        int cl = tid + t * 256;
        int row = cl >> 2, p = cl & 3;
        int rh, rl;
        if (row < 144) { rh = row; rl = row + 144; }
        else { int R = row - 144; rh = 288 + R; rl = 672 + R; }
        ldH[t] = rh * 32 + ((p ^ ((rh >> 1) & 3)) << 3);
        ldL[t] = rl * 32 + ((p ^ ((rl >> 1) & 3)) << 3);
        act[t] = 0; goH[t] = 0; goL[t] = 0;
        if (cl < 2112) {
            if (row < 144) {
                int s = s0 - 2 + row;
                if (s >= 0 && s < 1024) {
                    act[t] = 1;
                    unsigned int off = ((unsigned int)((b << 10) + s) << 10) + p * 8;
                    goH[t] = GH + off; goL[t] = GL + off;
                } else if (s < 0) {
                    act[t] = 2;                 // write zeros (causal pad)
                }                                // s>1023: rows never read -> skip
            } else {
                int R = row - 144;              // k*128 + o_local
                int k = R >> 7, ol = R & 127;
                act[t] = 1;
                unsigned int off = (unsigned int)k * 3145728u + ((unsigned int)(o0 + ol) << 10) + p * 8;
                goH[t] = WH + off; goL[t] = WL + off;
            }
        }
    }

    int aofH[3][4], aofL[3][4], bofH[3][4], bofL[3][4];
    #pragma unroll
    for (int k = 0; k < 3; ++k) {
        #pragma unroll
        for (int fm = 0; fm < 4; ++fm) {
            int R = k * 128 + wm + fm * 16 + lm;
            int rh = 288 + R, rl = 672 + R;
            aofH[k][fm] = rh * 32 + ((q ^ ((rh >> 1) & 3)) << 3);
            aofL[k][fm] = rl * 32 + ((q ^ ((rl >> 1) & 3)) << 3);
        }
        #pragma unroll
        for (int fn = 0; fn < 4; ++fn) {
            int rh = wn + fn * 16 + lm + k;     // tile row = s - s0 + 2, max 129
            int rl = rh + 144;
            bofH[k][fn] = rh * 32 + ((q ^ ((rh >> 1) & 3)) << 3);
            bofL[k][fn] = rl * 32 + ((q ^ ((rl >> 1) & 3)) << 3);
        }
    }

    f32x4 acc[4][4];
    #pragma unroll
    for (int fm = 0; fm < 4; ++fm)
        #pragma unroll
        for (int fn = 0; fn < 4; ++fn)
            acc[fm][fn] = (f32x4){0.f, 0.f, 0.f, 0.f};

    const short8 z = {0, 0, 0, 0, 0, 0, 0, 0};

    for (int i0 = 0; i0 < 1024; i0 += 32) {
        short8 vh[9], vl[9];
        #pragma unroll
        for (int t = 0; t < 9; ++t) vh[t] = (act[t] == 1) ? *(const short8*)(base + goH[t] + i0) : z;
        #pragma unroll
        for (int t = 0; t < 9; ++t) vl[t] = (act[t] == 1) ? *(const short8*)(base + goL[t] + i0) : z;
        __syncthreads();
        #pragma unroll
        for (int t = 0; t < 9; ++t)
            if (act[t]) {
                *(short8*)(lds + ldH[t]) = vh[t];
                *(short8*)(lds + ldL[t]) = vl[t];
            }
        __syncthreads();

        #pragma unroll
        for (int k = 0; k < 3; ++k) {
            short8 ah[4], al[4], bh[4], bl[4];
            #pragma unroll
            for (int fm = 0; fm < 4; ++fm) {
                ah[fm] = *(const short8*)(lds + aofH[k][fm]);
                al[fm] = *(const short8*)(lds + aofL[k][fm]);
            }
            #pragma unroll
            for (int fn = 0; fn < 4; ++fn) {
                bh[fn] = *(const short8*)(lds + bofH[k][fn]);
                bl[fn] = *(const short8*)(lds + bofL[k][fn]);
            }
            #pragma unroll
            for (int fm = 0; fm < 4; ++fm)
                #pragma unroll
                for (int fn = 0; fn < 4; ++fn) {
                    acc[fm][fn] = __builtin_amdgcn_mfma_f32_16x16x32_bf16(ah[fm], bh[fn], acc[fm][fn], 0, 0, 0);
                    acc[fm][fn] = __builtin_amdgcn_mfma_f32_16x16x32_bf16(ah[fm], bl[fn], acc[fm][fn], 0, 0, 0);
                    acc[fm][fn] = __builtin_amdgcn_mfma_f32_16x16x32_bf16(al[fm], bh[fn], acc[fm][fn], 0, 0, 0);
                }
        }
    }

    #pragma unroll
    for (int fm = 0; fm < 4; ++fm)
        #pragma unroll
        for (int fn = 0; fn < 4; ++fn) {
            int o = o0 + wm + fm * 16 + q * 4;
            int s = s0 + wn + fn * 16 + lm;
            float* op = co + ((size_t)b * 3072 + o) * SDIM + s;
            #pragma unroll
            for (int r = 0; r < 4; ++r)
                op[(size_t)r * SDIM] = acc[fm][fn][r];
        }
}

// ---------------- MoE2 plain-bf16 MFMA (value noise ok; no downstream argmax) --------
__global__ __launch_bounds__(256) void moe_kernel(
    const unsigned short* __restrict__ xT, const unsigned short* __restrict__ wT,
    const int* __restrict__ idx, float* __restrict__ out,
    int Fdim, int Ddim)
{
    __shared__ unsigned short lds[(128 + 512) * 32];
    int d0 = blockIdx.x * 128;
    int t0 = blockIdx.y * 128;
    int b = t0 >> 10, s0 = t0 & 1023;
    int tid = threadIdx.x;
    int lane = tid & 63, wid = tid >> 6;
    int lm = lane & 15, q = lane >> 4;
    int wm = (wid >> 1) * 64, wn = (wid & 1) * 64;

    const unsigned short* gsrc[10];
    int ldst[10];
    #pragma unroll
    for (int t = 0; t < 10; ++t) {
        int cl = tid + t * 256;
        int row = cl >> 2, p = cl & 3;
        ldst[t] = row * 32 + ((p ^ ((row >> 1) & 3)) << 3);
        if (row < 128) {
            gsrc[t] = xT + (size_t)((b << 10) + s0 + row) * Fdim + p * 8;
        } else {
            int R = row - 128;
            int e = R >> 7, dl = R & 127;
            gsrc[t] = wT + (size_t)(e * Ddim + d0 + dl) * Fdim + p * 8;
        }
    }

    int bof[4], aof[4][4];
    #pragma unroll
    for (int fn = 0; fn < 4; ++fn) {
        int row = wn + fn * 16 + lm;
        bof[fn] = row * 32 + ((q ^ ((row >> 1) & 3)) << 3);
    }
    #pragma unroll
    for (int e = 0; e < 4; ++e)
        #pragma unroll
        for (int fm = 0; fm < 4; ++fm) {
            int R = e * 128 + wm + fm * 16 + lm;
            aof[e][fm] = 4096 + R * 32 + ((q ^ ((R >> 1) & 3)) << 3);
        }

    int eidx[4];
    #pragma unroll
    for (int fn = 0; fn < 4; ++fn)
        eidx[fn] = idx[(b << 10) + s0 + wn + fn * 16 + lm];

    f32x4 acc[4][4];
    #pragma unroll
    for (int fm = 0; fm < 4; ++fm)
        #pragma unroll
        for (int fn = 0; fn < 4; ++fn)
            acc[fm][fn] = (f32x4){0.f, 0.f, 0.f, 0.f};

    const short8 z = {0, 0, 0, 0, 0, 0, 0, 0};

    for (int f0 = 0; f0 < Fdim; f0 += 32) {
        short8 v[10];
        #pragma unroll
        for (int t = 0; t < 10; ++t)
            v[t] = *(const short8*)(gsrc[t] + f0);
        __syncthreads();
        #pragma unroll
        for (int t = 0; t < 10; ++t)
            *(short8*)(lds + ldst[t]) = v[t];
        __syncthreads();

        short8 bf[4];
        #pragma unroll
        for (int fn = 0; fn < 4; ++fn)
            bf[fn] = *(const short8*)(lds + bof[fn]);
        #pragma unroll
        for (int e = 0; e < 4; ++e) {
            short8 af[4];
            #pragma unroll
            for (int fm = 0; fm < 4; ++fm)
                af[fm] = *(const short8*)(lds + aof[e][fm]);
            #pragma unroll
            for (int fn = 0; fn < 4; ++fn) {
                short8 bm = (eidx[fn] == e) ? bf[fn] : z;
                #pragma unroll
                for (int fm = 0; fm < 4; ++fm)
                    acc[fm][fn] = __builtin_amdgcn_mfma_f32_16x16x32_bf16(af[fm], bm, acc[fm][fn], 0, 0, 0);
            }
        }
    }

    #pragma unroll
    for (int fm = 0; fm < 4; ++fm)
        #pragma unroll
        for (int fn = 0; fn < 4; ++fn) {
            int d = d0 + wm + fm * 16 + q * 4;
            int s = s0 + wn + fn * 16 + lm;
            float* op = out + ((size_t)b * Ddim + d) * SDIM + s;
            #pragma unroll
            for (int r = 0; r < 4; ++r)
                op[(size_t)r * SDIM] = acc[fm][fn][r];
        }
}

// ---------------- cumsum over s + affine ----------------
__global__ __launch_bounds__(256) void cumsum_affine_kernel(
    const float* __restrict__ h1, const float* __restrict__ divisor,
    float* __restrict__ y)
{
    int r = blockIdx.x;
    int b = r >> 10, i = r & 1023;
    const float4* dp = (const float4*)(h1 + ((size_t)b * 3072 + i) * SDIM);
    const float4* sp = (const float4*)(h1 + ((size_t)b * 3072 + 1024 + i) * SDIM);
    const float4* hp = (const float4*)(h1 + ((size_t)b * 3072 + 2048 + i) * SDIM);
    int tid = threadIdx.x;
    float4 v = dp[tid];
    float c0 = v.x, c1 = c0 + v.y, c2 = c1 + v.z, c3 = c2 + v.w;
    __shared__ float part[256];
    part[tid] = c3;
    __syncthreads();
    for (int off = 1; off < 256; off <<= 1) {
        float p = (tid >= off) ? part[tid - off] : 0.f;
        __syncthreads();
        part[tid] += p;
        __syncthreads();
    }
    float base = part[tid] - c3;
    float4 sc = sp[tid], sh = hp[tid];
    float4 dv = ((const float4*)divisor)[tid];
    float4 o;
    o.x = (base + c0) / dv.x * sc.x + sh.x;
    o.y = (base + c1) / dv.y * sc.y + sh.y;
    o.z = (base + c2) / dv.z * sc.z + sh.z;
    o.w = (base + c3) / dv.w * sc.w + sh.w;
    ((float4*)(y + ((size_t)b * 1024 + i) * SDIM))[tid] = o;
}

// ---------------- channel norm (over i=1024) + leaky relu ----------------
// mode 0: v = in[b,i,s] (in [B,1024,S]); write split bf16 outH/outL [b][s][i]
// mode 1: v = in[b,i,s]*in[b,1024+i,s]+in[b,2048+i,s]; write fp32 outF + bf16 outH
__global__ __launch_bounds__(256) void norm_kernel(
    const float* __restrict__ in, float* __restrict__ outF,
    unsigned short* __restrict__ outH, unsigned short* __restrict__ outL, int mode)
{
    int blk = blockIdx.x;
    int b = blk >> 6;
    int s0 = (blk & 63) * 16;
    int tid = threadIdx.x;
    int sg = tid & 15, grp = tid >> 4;
    int s = s0 + sg;
    int instr = mode ? 3072 : 1024;
    const float* base0 = in + ((size_t)b * instr) * SDIM + s;
    float sum = 0.f, ssq = 0.f;
    for (int i = grp * 64; i < grp * 64 + 64; ++i) {
        float v;
        if (mode == 0) v = base0[(size_t)i * SDIM];
        else {
            float a  = base0[(size_t)i * SDIM];
            float m2 = base0[(size_t)(1024 + i) * SDIM];
            float d2 = base0[(size_t)(2048 + i) * SDIM];
            v = a * m2 + d2;
        }
        sum += v; ssq += v * v;
    }
    __shared__ float rs[16][16], rq[16][16], stat[2][16];
    rs[grp][sg] = sum; rq[grp][sg] = ssq;
    __syncthreads();
    for (int h = 8; h >= 1; h >>= 1) {
        if (grp < h) {
            rs[grp][sg] += rs[grp + h][sg];
            rq[grp][sg] += rq[grp + h][sg];
        }
        __syncthreads();
    }
    if (grp == 0) {
        float S1 = rs[0][sg], S2 = rq[0][sg];
        float mean = S1 * (1.0f / 1024.0f);
        float ssc = fmaxf(S2 - 1024.0f * mean * mean, 0.0f);
        stat[0][sg] = mean;
        stat[1][sg] = 1.0f / (sqrtf(ssc) * (1.0f / 32.0f) + 1e-5f);
    }
    __syncthreads();
    float mean = stat[0][sg], inv = stat[1][sg];
    unsigned short* tpH = outH + (((size_t)b << 10) + s) * 1024;
    unsigned short* tpL = outL ? outL + (((size_t)b << 10) + s) * 1024 : nullptr;
    for (int j0 = 0; j0 < 64; j0 += 4) {
        unsigned short uh[4], ul[4];
        #pragma unroll
        for (int jj = 0; jj < 4; ++jj) {
            int i = grp * 64 + j0 + jj;
            float v;
            if (mode == 0) v = base0[(size_t)i * SDIM];
            else {
                float a  = base0[(size_t)i * SDIM];
                float m2 = base0[(size_t)(1024 + i) * SDIM];
                float d2 = base0[(size_t)(2048 + i) * SDIM];
                v = a * m2 + d2;
            }
            float o = (v - mean) * inv;
            o = (o >= 0.f) ? o : 0.02f * o;
            if (outF) outF[((size_t)b * 1024 + i) * SDIM + s] = o;
            uh[jj] = f2bf(o);
            ul[jj] = f2bf(o - bf2f(uh[jj]));
        }
        ushort4 pkh = {uh[0], uh[1], uh[2], uh[3]};
        *(ushort4*)(tpH + grp * 64 + j0) = pkh;
        if (tpL) {
            ushort4 pkl = {ul[0], ul[1], ul[2], ul[3]};
            *(ushort4*)(tpL + grp * 64 + j0) = pkl;
        }
    }
}

// ---------------- final loss ----------------
__global__ void loss_kernel(const float* __restrict__ acc, float* __restrict__ out) {
    if (threadIdx.x == 0) {
        float l = 0.f;
        for (int e = 0; e < 4; ++e)
            l += acc[e] * acc[4 + e] + acc[8 + e] * acc[12 + e];
        out[2 * 512 * 1024] = l * (1.0f / (2048.0f * 2048.0f));
    }
}

extern "C" void kernel_launch(void* const* d_in, const int* in_sizes, int n_in,
                              void* d_out, int out_size, void* d_ws, size_t ws_size,
                              hipStream_t stream) {
    const float* inp     = (const float*)d_in[0];
    const float* divisor = (const float*)d_in[1];
    const float* w0_gate = (const float*)d_in[2];
    const float* w0      = (const float*)d_in[3];
    const float* w1      = (const float*)d_in[4];
    const float* w2_gate = (const float*)d_in[5];
    const float* w2      = (const float*)d_in[6];
    float* out = (float*)d_out;
    (void)in_sizes; (void)n_in; (void)out_size; (void)ws_size;

    char* ws = (char*)d_ws;
    const unsigned short* base = (const unsigned short*)ws;

    // byte offsets
    float* h1            = (float*)(ws + 0);                  // 25165824
    float* g             = (float*)(ws + 25165824);           //  8388608
    unsigned short* gT1h = (unsigned short*)(ws + 33554432);  //  4194304
    unsigned short* gT1l = (unsigned short*)(ws + 37748736);  //  4194304
    unsigned short* w1Th = (unsigned short*)(ws + 41943040);  // 18874368
    unsigned short* w1Tl = (unsigned short*)(ws + 60817408);  // 18874368
    unsigned short* xTh  = (unsigned short*)(ws + 79691776);  //  2097152
    unsigned short* xTl  = (unsigned short*)(ws + 81788928);  //  2097152
    unsigned short* w0Th = (unsigned short*)(ws + 83886080);  // 12582912
    unsigned short* w0Tl = (unsigned short*)(ws + 96468992);  // 12582912
    // overlapped (alive only after moe1 consumed xT/w0T):
    unsigned short* gT2  = (unsigned short*)(ws + 79691776);  //  4194304
    unsigned short* w2T  = (unsigned short*)(ws + 83886080);  //  4194304
    int* idx1            = (int*)(ws + 109051904);
    int* idx2            = (int*)(ws + 109060096);
    float* acc           = (float*)(ws + 109068288);

    // element offsets (ushort units) for MFMA kernels
    const unsigned int GT1H = 16777216u, GT1L = 18874368u;
    const unsigned int W1TH = 20971520u, W1TL = 30408704u;
    const unsigned int XTH  = 39845888u, XTL  = 40894464u;
    const unsigned int W0TH = 41943040u, W0TL = 48234496u;

    init_acc_kernel<<<1, 16, 0, stream>>>(acc);

    // split bf16 operand prep for MoE1 + conv
    transpose_cvt_split<<<dim3(32, 16, 2), 256, 0, stream>>>(inp, xTh, xTl, 512, 1024, (size_t)512 * 1024);
    transpose_cvt_split<<<dim3(96, 16, 4), 256, 0, stream>>>(w0, w0Th, w0Tl, 512, 3072, (size_t)512 * 3072);
    w1cvt_split_kernel<<<12288, 256, 0, stream>>>(w1, w1Th, w1Tl);

    // MoE 1 (split, fp32-accurate)
    gate_kernel<<<64, 256, 0, stream>>>(inp, w0_gate, idx1, acc, 512, 0);
    moe_split_kernel<<<dim3(24, 16), 256, 0, stream>>>(base, XTH, XTL, W0TH, W0TL, idx1, h1, 512, 3072);

    // w2 -> w2T (plain bf16); placed after MoE1 because w2T overlaps w0Th
    transpose_cvt<<<dim3(16, 32, 4), 256, 0, stream>>>(w2, w2T, 1024, 512, (size_t)1024 * 512);

    // cumsum + affine -> g (fp32)
    cumsum_affine_kernel<<<2048, 256, 0, stream>>>(h1, divisor, g);
    // norm + leaky -> gT1 hi/lo (split bf16, [b][s][i])
    norm_kernel<<<128, 256, 0, stream>>>(g, nullptr, gT1h, gT1l, 0);
    // conv (split, fp32-accurate) -> h1
    conv_split_kernel<<<dim3(24, 16), 256, 0, stream>>>(base, GT1H, GT1L, W1TH, W1TL, h1);
    // gated combine + norm + leaky -> g (fp32, for gate2) + gT2 (plain bf16)
    norm_kernel<<<128, 256, 0, stream>>>(h1, g, gT2, nullptr, 1);

    // MoE 2 (plain bf16)
    gate_kernel<<<64, 256, 0, stream>>>(g, w2_gate, idx2, acc, 1024, 8);
    moe_kernel<<<dim3(4, 16), 256, 0, stream>>>(gT2, w2T, idx2, out, 1024, 512);
    loss_kernel<<<1, 64, 0, stream>>>(acc, out);
}

// Round 5
// 337.961 us; speedup vs baseline: 7.1291x; 1.3811x over previous
//
#include <hip/hip_runtime.h>
#include <hip/hip_bf16.h>

#define SDIM 1024

typedef float f32x4 __attribute__((ext_vector_type(4)));
typedef short short8 __attribute__((ext_vector_type(8)));

__device__ __forceinline__ unsigned short f2bf(float f) {
    __hip_bfloat16 h = __float2bfloat16(f);
    return *reinterpret_cast<unsigned short*>(&h);
}
__device__ __forceinline__ float bf2f(unsigned short u) {
    return __uint_as_float(((unsigned int)u) << 16);
}

// ---------------- init ----------------
__global__ void init_acc_kernel(float* acc) {
    int t = threadIdx.x;
    if (t < 16) acc[t] = 0.0f;
}

// ------- transpose + split cvt: fp32 [slice][R][C] -> bf16 hi/lo [slice][C][R] -------
__global__ __launch_bounds__(256) void transpose_cvt_split(
    const float* __restrict__ in, unsigned short* __restrict__ oh,
    unsigned short* __restrict__ ol, int R, int C, size_t sliceStride)
{
    __shared__ float t[32][33];
    int slice = blockIdx.z;
    int c0 = blockIdx.x * 32, r0 = blockIdx.y * 32;
    int tid = threadIdx.x;
    int cc = tid & 31, r8 = tid >> 5;
    const float* ip = in + slice * sliceStride;
    #pragma unroll
    for (int k = 0; k < 4; ++k) {
        int r = r8 + k * 8;
        t[r][cc] = ip[(size_t)(r0 + r) * C + c0 + cc];
    }
    __syncthreads();
    #pragma unroll
    for (int k = 0; k < 4; ++k) {
        int rr = r8 + k * 8;
        float v = t[cc][rr];
        unsigned short hi = f2bf(v);
        unsigned short lo = f2bf(v - bf2f(hi));
        size_t o = slice * sliceStride + (size_t)(c0 + rr) * R + r0 + cc;
        oh[o] = hi; ol[o] = lo;
    }
}

// ------- plain transpose + cvt (for w2) -------
__global__ __launch_bounds__(256) void transpose_cvt(
    const float* __restrict__ in, unsigned short* __restrict__ out,
    int R, int C, size_t sliceStride)
{
    __shared__ float t[32][33];
    int slice = blockIdx.z;
    int c0 = blockIdx.x * 32, r0 = blockIdx.y * 32;
    int tid = threadIdx.x;
    int cc = tid & 31, r8 = tid >> 5;
    const float* ip = in + slice * sliceStride;
    unsigned short* op = out + slice * sliceStride;
    #pragma unroll
    for (int k = 0; k < 4; ++k) {
        int r = r8 + k * 8;
        t[r][cc] = ip[(size_t)(r0 + r) * C + c0 + cc];
    }
    __syncthreads();
    #pragma unroll
    for (int k = 0; k < 4; ++k) {
        int rr = r8 + k * 8;
        op[(size_t)(c0 + rr) * R + r0 + cc] = f2bf(t[cc][rr]);
    }
}

// ------- w1 split cvt: [3072][1024][3] fp32 -> [3][3072][1024] bf16 hi/lo -------
__global__ __launch_bounds__(256) void w1cvt_split_kernel(
    const float* __restrict__ w1, unsigned short* __restrict__ wh,
    unsigned short* __restrict__ wl)
{
    int t = blockIdx.x * 256 + threadIdx.x;
    int o = t >> 10, i = t & 1023;
    const float* p = w1 + (size_t)o * 3072 + i * 3;
    #pragma unroll
    for (int k = 0; k < 3; ++k) {
        float v = p[k];
        unsigned short hi = f2bf(v);
        unsigned short lo = f2bf(v - bf2f(hi));
        size_t off = (size_t)k * 3145728 + (size_t)o * 1024 + i;
        wh[off] = hi; wl[off] = lo;
    }
}

// ---------------- gate1: logits, softmax means, argmax (fp32) ----------------
__global__ __launch_bounds__(256) void gate_kernel(
    const float* __restrict__ x, const float* __restrict__ wg,
    int* __restrict__ idx, float* __restrict__ acc, int F, int accBase)
{
    __shared__ float wgs[4 * 1024];
    __shared__ float part[8][4][33];
    __shared__ float la[8];
    int tid = threadIdx.x;
    if (tid < 8) la[tid] = 0.f;
    for (int l = tid; l < 4 * F; l += 256) wgs[l] = wg[l];
    __syncthreads();
    int t0 = blockIdx.x * 32;
    int b = t0 >> 10, s0 = t0 & 1023;
    int sl = tid & 31, fg = tid >> 5;
    float l0 = 0.f, l1 = 0.f, l2 = 0.f, l3 = 0.f;
    for (int f = fg; f < F; f += 8) {
        float xv = x[((size_t)b * F + f) * SDIM + s0 + sl];
        l0 += xv * wgs[f];
        l1 += xv * wgs[F + f];
        l2 += xv * wgs[2 * F + f];
        l3 += xv * wgs[3 * F + f];
    }
    part[fg][0][sl] = l0; part[fg][1][sl] = l1;
    part[fg][2][sl] = l2; part[fg][3][sl] = l3;
    __syncthreads();
    if (fg == 0) {
        float L[4];
        #pragma unroll
        for (int e = 0; e < 4; ++e) {
            float v = 0.f;
            #pragma unroll
            for (int g2 = 0; g2 < 8; ++g2) v += part[g2][e][sl];
            L[e] = v;
        }
        float m = fmaxf(fmaxf(L[0], L[1]), fmaxf(L[2], L[3]));
        float e0 = expf(L[0] - m), e1 = expf(L[1] - m), e2 = expf(L[2] - m), e3 = expf(L[3] - m);
        float inv = 1.0f / (e0 + e1 + e2 + e3);
        int best = 0; float bv = L[0];
        if (L[1] > bv) { bv = L[1]; best = 1; }
        if (L[2] > bv) { bv = L[2]; best = 2; }
        if (L[3] > bv) { bv = L[3]; best = 3; }
        idx[t0 + sl] = best;
        atomicAdd(&la[0], e0 * inv);
        atomicAdd(&la[1], e1 * inv);
        atomicAdd(&la[2], e2 * inv);
        atomicAdd(&la[3], e3 * inv);
        atomicAdd(&la[4 + best], 1.0f);
    }
    __syncthreads();
    if (tid < 8) atomicAdd(&acc[accBase + tid], la[tid]);
}

// ---------------- MoE1 split-bf16 MFMA, 64d x 128tok tiles ----------------
// LDS rows(64B): Xh[0,128) Xl[128,256) Wh[256,512) Wl[512,768)
__global__ __launch_bounds__(256) void moe_split_kernel(
    const unsigned short* __restrict__ base, unsigned int XH, unsigned int XL,
    unsigned int WH, unsigned int WL,
    const int* __restrict__ idx, float* __restrict__ out,
    int Fdim, int Ddim, int dT)
{
    __shared__ unsigned short lds[768 * 32];   // 48 KiB
    int chunk = gridDim.x >> 3;
    int id = blockIdx.x;
    int wg = (id & 7) * chunk + (id >> 3);     // XCD-contiguous
    int d0 = (wg % dT) * 64;
    int t0 = (wg / dT) * 128;
    int b = t0 >> 10, s0 = t0 & 1023;
    int tid = threadIdx.x;
    int lane = tid & 63;
    int lm = lane & 15, q = lane >> 4;
    int wid = tid >> 6;
    int wm = (wid >> 1) * 32, wn = (wid & 1) * 64;

    unsigned int goH[6], goL[6];
    int ldH[6], ldL[6];
    #pragma unroll
    for (int t = 0; t < 6; ++t) {
        int cl = tid + t * 256;          // 0..1535
        int row = cl >> 2, p = cl & 3;
        int rh, rl;
        unsigned int off;
        if (row < 128) {
            off = (unsigned int)(((b << 10) + s0 + row) * Fdim + p * 8);
            goH[t] = XH + off; goL[t] = XL + off;
            rh = row; rl = row + 128;
        } else {
            int R = row - 128;           // e*64 + d_local
            int e = R >> 6, dl = R & 63;
            off = (unsigned int)((e * Ddim + d0 + dl) * Fdim + p * 8);
            goH[t] = WH + off; goL[t] = WL + off;
            rh = 256 + R; rl = 512 + R;
        }
        ldH[t] = rh * 32 + ((p ^ ((rh >> 1) & 3)) << 3);
        ldL[t] = rl * 32 + ((p ^ ((rl >> 1) & 3)) << 3);
    }

    int bofH[4], bofL[4], aofH[4][2], aofL[4][2];
    #pragma unroll
    for (int fn = 0; fn < 4; ++fn) {
        int rh = wn + fn * 16 + lm, rl = rh + 128;
        bofH[fn] = rh * 32 + ((q ^ ((rh >> 1) & 3)) << 3);
        bofL[fn] = rl * 32 + ((q ^ ((rl >> 1) & 3)) << 3);
    }
    #pragma unroll
    for (int e = 0; e < 4; ++e)
        #pragma unroll
        for (int fm = 0; fm < 2; ++fm) {
            int rh = 256 + e * 64 + wm + fm * 16 + lm;
            int rl = rh + 256;
            aofH[e][fm] = rh * 32 + ((q ^ ((rh >> 1) & 3)) << 3);
            aofL[e][fm] = rl * 32 + ((q ^ ((rl >> 1) & 3)) << 3);
        }

    int eidx[4];
    #pragma unroll
    for (int fn = 0; fn < 4; ++fn)
        eidx[fn] = idx[(b << 10) + s0 + wn + fn * 16 + lm];

    f32x4 acc[2][4];
    #pragma unroll
    for (int fm = 0; fm < 2; ++fm)
        #pragma unroll
        for (int fn = 0; fn < 4; ++fn)
            acc[fm][fn] = (f32x4){0.f, 0.f, 0.f, 0.f};

    const short8 z = {0, 0, 0, 0, 0, 0, 0, 0};

    for (int f0 = 0; f0 < Fdim; f0 += 32) {
        short8 vh[6], vl[6];
        #pragma unroll
        for (int t = 0; t < 6; ++t) vh[t] = *(const short8*)(base + goH[t] + f0);
        #pragma unroll
        for (int t = 0; t < 6; ++t) vl[t] = *(const short8*)(base + goL[t] + f0);
        __syncthreads();
        #pragma unroll
        for (int t = 0; t < 6; ++t) {
            *(short8*)(lds + ldH[t]) = vh[t];
            *(short8*)(lds + ldL[t]) = vl[t];
        }
        __syncthreads();

        short8 bh[4], bl[4];
        #pragma unroll
        for (int fn = 0; fn < 4; ++fn) {
            bh[fn] = *(const short8*)(lds + bofH[fn]);
            bl[fn] = *(const short8*)(lds + bofL[fn]);
        }
        #pragma unroll
        for (int e = 0; e < 4; ++e) {
            short8 ah[2], al[2];
            #pragma unroll
            for (int fm = 0; fm < 2; ++fm) {
                ah[fm] = *(const short8*)(lds + aofH[e][fm]);
                al[fm] = *(const short8*)(lds + aofL[e][fm]);
            }
            #pragma unroll
            for (int fn = 0; fn < 4; ++fn) {
                short8 bmH = (eidx[fn] == e) ? bh[fn] : z;
                short8 bmL = (eidx[fn] == e) ? bl[fn] : z;
                #pragma unroll
                for (int fm = 0; fm < 2; ++fm) {
                    acc[fm][fn] = __builtin_amdgcn_mfma_f32_16x16x32_bf16(ah[fm], bmH, acc[fm][fn], 0, 0, 0);
                    acc[fm][fn] = __builtin_amdgcn_mfma_f32_16x16x32_bf16(ah[fm], bmL, acc[fm][fn], 0, 0, 0);
                    acc[fm][fn] = __builtin_amdgcn_mfma_f32_16x16x32_bf16(al[fm], bmH, acc[fm][fn], 0, 0, 0);
                }
            }
        }
        __syncthreads();
    }

    #pragma unroll
    for (int fm = 0; fm < 2; ++fm)
        #pragma unroll
        for (int fn = 0; fn < 4; ++fn) {
            int d = d0 + wm + fm * 16 + q * 4;
            int s = s0 + wn + fn * 16 + lm;
            float* op = out + ((size_t)b * Ddim + d) * SDIM + s;
            #pragma unroll
            for (int r = 0; r < 4; ++r)
                op[(size_t)r * SDIM] = acc[fm][fn][r];
        }
}

// ---------------- conv1d K=3 split-bf16 MFMA, 64o x 128tok tiles ----------------
// LDS rows(64B): Gh[0,144) Gl[144,288) Wh[288,480) Wl[480,672)
__global__ __launch_bounds__(256) void conv_split_kernel(
    const unsigned short* __restrict__ base, unsigned int GH, unsigned int GL,
    unsigned int WH, unsigned int WL, float* __restrict__ co)
{
    __shared__ unsigned short lds[672 * 32];   // 42 KiB
    int id = blockIdx.x;
    int wg = (id & 7) * 96 + (id >> 3);        // 768 blocks, XCD-contiguous
    int o0 = (wg % 48) * 64;
    int t0 = (wg / 48) * 128;
    int b = t0 >> 10, s0 = t0 & 1023;
    int tid = threadIdx.x;
    int lane = tid & 63;
    int lm = lane & 15, q = lane >> 4;
    int wid = tid >> 6;
    int wm = (wid >> 1) * 32, wn = (wid & 1) * 64;

    unsigned int goH[6], goL[6];
    int ldH[6], ldL[6], act[6];
    #pragma unroll
    for (int t = 0; t < 6; ++t) {
        int cl = tid + t * 256;
        int row = cl >> 2, p = cl & 3;
        int rh, rl;
        if (row < 144) { rh = row; rl = row + 144; }
        else { int R = row - 144; rh = 288 + R; rl = 480 + R; }
        ldH[t] = rh * 32 + ((p ^ ((rh >> 1) & 3)) << 3);
        ldL[t] = rl * 32 + ((p ^ ((rl >> 1) & 3)) << 3);
        act[t] = 0; goH[t] = 0; goL[t] = 0;
        if (cl < 1344) {
            if (row < 144) {
                int s = s0 - 2 + row;
                if (s >= 0 && s < 1024) {
                    act[t] = 1;
                    unsigned int off = ((unsigned int)((b << 10) + s) << 10) + p * 8;
                    goH[t] = GH + off; goL[t] = GL + off;
                } else if (s < 0) {
                    act[t] = 2;                 // causal zero pad
                }
            } else {
                int R = row - 144;              // k*64 + o_local
                int k = R >> 6, ol = R & 63;
                act[t] = 1;
                unsigned int off = (unsigned int)k * 3145728u + ((unsigned int)(o0 + ol) << 10) + p * 8;
                goH[t] = WH + off; goL[t] = WL + off;
            }
        }
    }

    int aofH[3][2], aofL[3][2], bofH[3][4], bofL[3][4];
    #pragma unroll
    for (int k = 0; k < 3; ++k) {
        #pragma unroll
        for (int fm = 0; fm < 2; ++fm) {
            int R = k * 64 + wm + fm * 16 + lm;
            int rh = 288 + R, rl = 480 + R;
            aofH[k][fm] = rh * 32 + ((q ^ ((rh >> 1) & 3)) << 3);
            aofL[k][fm] = rl * 32 + ((q ^ ((rl >> 1) & 3)) << 3);
        }
        #pragma unroll
        for (int fn = 0; fn < 4; ++fn) {
            int rh = wn + fn * 16 + lm + k;     // tile row = s - s0 + 2
            int rl = rh + 144;
            bofH[k][fn] = rh * 32 + ((q ^ ((rh >> 1) & 3)) << 3);
            bofL[k][fn] = rl * 32 + ((q ^ ((rl >> 1) & 3)) << 3);
        }
    }

    f32x4 acc[2][4];
    #pragma unroll
    for (int fm = 0; fm < 2; ++fm)
        #pragma unroll
        for (int fn = 0; fn < 4; ++fn)
            acc[fm][fn] = (f32x4){0.f, 0.f, 0.f, 0.f};

    const short8 z = {0, 0, 0, 0, 0, 0, 0, 0};

    for (int i0 = 0; i0 < 1024; i0 += 32) {
        short8 vh[6], vl[6];
        #pragma unroll
        for (int t = 0; t < 6; ++t) vh[t] = (act[t] == 1) ? *(const short8*)(base + goH[t] + i0) : z;
        #pragma unroll
        for (int t = 0; t < 6; ++t) vl[t] = (act[t] == 1) ? *(const short8*)(base + goL[t] + i0) : z;
        __syncthreads();
        #pragma unroll
        for (int t = 0; t < 6; ++t)
            if (act[t]) {
                *(short8*)(lds + ldH[t]) = vh[t];
                *(short8*)(lds + ldL[t]) = vl[t];
            }
        __syncthreads();

        #pragma unroll
        for (int k = 0; k < 3; ++k) {
            short8 ah[2], al[2], bh[4], bl[4];
            #pragma unroll
            for (int fm = 0; fm < 2; ++fm) {
                ah[fm] = *(const short8*)(lds + aofH[k][fm]);
                al[fm] = *(const short8*)(lds + aofL[k][fm]);
            }
            #pragma unroll
            for (int fn = 0; fn < 4; ++fn) {
                bh[fn] = *(const short8*)(lds + bofH[k][fn]);
                bl[fn] = *(const short8*)(lds + bofL[k][fn]);
            }
            #pragma unroll
            for (int fm = 0; fm < 2; ++fm)
                #pragma unroll
                for (int fn = 0; fn < 4; ++fn) {
                    acc[fm][fn] = __builtin_amdgcn_mfma_f32_16x16x32_bf16(ah[fm], bh[fn], acc[fm][fn], 0, 0, 0);
                    acc[fm][fn] = __builtin_amdgcn_mfma_f32_16x16x32_bf16(ah[fm], bl[fn], acc[fm][fn], 0, 0, 0);
                    acc[fm][fn] = __builtin_amdgcn_mfma_f32_16x16x32_bf16(al[fm], bh[fn], acc[fm][fn], 0, 0, 0);
                }
        }
    }

    #pragma unroll
    for (int fm = 0; fm < 2; ++fm)
        #pragma unroll
        for (int fn = 0; fn < 4; ++fn) {
            int o = o0 + wm + fm * 16 + q * 4;
            int s = s0 + wn + fn * 16 + lm;
            float* op = co + ((size_t)b * 3072 + o) * SDIM + s;
            #pragma unroll
            for (int r = 0; r < 4; ++r)
                op[(size_t)r * SDIM] = acc[fm][fn][r];
        }
}

// ---------------- MoE2 plain-bf16 MFMA, 64d x 128tok ----------------
// LDS rows(64B): X[0,128) W[128,384)
__global__ __launch_bounds__(256) void moe_kernel(
    const unsigned short* __restrict__ xT, const unsigned short* __restrict__ wT,
    const int* __restrict__ idx, float* __restrict__ out,
    int Fdim, int Ddim, int dT)
{
    __shared__ unsigned short lds[384 * 32];   // 24 KiB
    int chunk = gridDim.x >> 3;
    int id = blockIdx.x;
    int wg = (id & 7) * chunk + (id >> 3);
    int d0 = (wg % dT) * 64;
    int t0 = (wg / dT) * 128;
    int b = t0 >> 10, s0 = t0 & 1023;
    int tid = threadIdx.x;
    int lane = tid & 63, wid = tid >> 6;
    int lm = lane & 15, q = lane >> 4;
    int wm = (wid >> 1) * 32, wn = (wid & 1) * 64;

    const unsigned short* gsrc[6];
    int ldst[6];
    #pragma unroll
    for (int t = 0; t < 6; ++t) {
        int cl = tid + t * 256;          // 0..1535
        int row = cl >> 2, p = cl & 3;
        int pr;
        if (row < 128) {
            gsrc[t] = xT + (size_t)((b << 10) + s0 + row) * Fdim + p * 8;
            pr = row;
        } else {
            int R = row - 128;           // e*64 + dl
            int e = R >> 6, dl = R & 63;
            gsrc[t] = wT + (size_t)(e * Ddim + d0 + dl) * Fdim + p * 8;
            pr = 128 + R;
        }
        ldst[t] = pr * 32 + ((p ^ ((pr >> 1) & 3)) << 3);
    }

    int bof[4], aof[4][2];
    #pragma unroll
    for (int fn = 0; fn < 4; ++fn) {
        int row = wn + fn * 16 + lm;
        bof[fn] = row * 32 + ((q ^ ((row >> 1) & 3)) << 3);
    }
    #pragma unroll
    for (int e = 0; e < 4; ++e)
        #pragma unroll
        for (int fm = 0; fm < 2; ++fm) {
            int R = 128 + e * 64 + wm + fm * 16 + lm;
            aof[e][fm] = R * 32 + ((q ^ ((R >> 1) & 3)) << 3);
        }

    int eidx[4];
    #pragma unroll
    for (int fn = 0; fn < 4; ++fn)
        eidx[fn] = idx[(b << 10) + s0 + wn + fn * 16 + lm];

    f32x4 acc[2][4];
    #pragma unroll
    for (int fm = 0; fm < 2; ++fm)
        #pragma unroll
        for (int fn = 0; fn < 4; ++fn)
            acc[fm][fn] = (f32x4){0.f, 0.f, 0.f, 0.f};

    const short8 z = {0, 0, 0, 0, 0, 0, 0, 0};

    for (int f0 = 0; f0 < Fdim; f0 += 32) {
        short8 v[6];
        #pragma unroll
        for (int t = 0; t < 6; ++t)
            v[t] = *(const short8*)(gsrc[t] + f0);
        __syncthreads();
        #pragma unroll
        for (int t = 0; t < 6; ++t)
            *(short8*)(lds + ldst[t]) = v[t];
        __syncthreads();

        short8 bf[4];
        #pragma unroll
        for (int fn = 0; fn < 4; ++fn)
            bf[fn] = *(const short8*)(lds + bof[fn]);
        #pragma unroll
        for (int e = 0; e < 4; ++e) {
            short8 af[2];
            #pragma unroll
            for (int fm = 0; fm < 2; ++fm)
                af[fm] = *(const short8*)(lds + aof[e][fm]);
            #pragma unroll
            for (int fn = 0; fn < 4; ++fn) {
                short8 bm = (eidx[fn] == e) ? bf[fn] : z;
                #pragma unroll
                for (int fm = 0; fm < 2; ++fm)
                    acc[fm][fn] = __builtin_amdgcn_mfma_f32_16x16x32_bf16(af[fm], bm, acc[fm][fn], 0, 0, 0);
            }
        }
    }

    #pragma unroll
    for (int fm = 0; fm < 2; ++fm)
        #pragma unroll
        for (int fn = 0; fn < 4; ++fn) {
            int d = d0 + wm + fm * 16 + q * 4;
            int s = s0 + wn + fn * 16 + lm;
            float* op = out + ((size_t)b * Ddim + d) * SDIM + s;
            #pragma unroll
            for (int r = 0; r < 4; ++r)
                op[(size_t)r * SDIM] = acc[fm][fn][r];
        }
}

// ---------------- cumsum over s + affine ----------------
__global__ __launch_bounds__(256) void cumsum_affine_kernel(
    const float* __restrict__ h1, const float* __restrict__ divisor,
    float* __restrict__ y)
{
    int r = blockIdx.x;
    int b = r >> 10, i = r & 1023;
    const float4* dp = (const float4*)(h1 + ((size_t)b * 3072 + i) * SDIM);
    const float4* sp = (const float4*)(h1 + ((size_t)b * 3072 + 1024 + i) * SDIM);
    const float4* hp = (const float4*)(h1 + ((size_t)b * 3072 + 2048 + i) * SDIM);
    int tid = threadIdx.x;
    float4 v = dp[tid];
    float c0 = v.x, c1 = c0 + v.y, c2 = c1 + v.z, c3 = c2 + v.w;
    __shared__ float part[256];
    part[tid] = c3;
    __syncthreads();
    for (int off = 1; off < 256; off <<= 1) {
        float p = (tid >= off) ? part[tid - off] : 0.f;
        __syncthreads();
        part[tid] += p;
        __syncthreads();
    }
    float base = part[tid] - c3;
    float4 sc = sp[tid], sh = hp[tid];
    float4 dv = ((const float4*)divisor)[tid];
    float4 o;
    o.x = (base + c0) / dv.x * sc.x + sh.x;
    o.y = (base + c1) / dv.y * sc.y + sh.y;
    o.z = (base + c2) / dv.z * sc.z + sh.z;
    o.w = (base + c3) / dv.w * sc.w + sh.w;
    ((float4*)(y + ((size_t)b * 1024 + i) * SDIM))[tid] = o;
}

// ---------------- norm0: channel norm + leaky, split bf16 out [b][s][i] --------------
// in g fp32 [B,1024,S]; 256 blocks = B*128 s-tiles of 8; 256 thr = 8 sg x 32 grp
__global__ __launch_bounds__(256) void norm0_kernel(
    const float* __restrict__ g, unsigned short* __restrict__ oh,
    unsigned short* __restrict__ ol)
{
    int blk = blockIdx.x;
    int b = blk >> 7;
    int s0 = (blk & 127) * 8;
    int tid = threadIdx.x;
    int sg = tid & 7, grp = tid >> 3;
    int s = s0 + sg;
    const float* bp = g + ((size_t)b * 1024) * SDIM + s;
    float v[32];
    float sum = 0.f, ssq = 0.f;
    #pragma unroll
    for (int j = 0; j < 32; ++j) {
        float x = bp[(size_t)(grp * 32 + j) * SDIM];
        v[j] = x; sum += x; ssq += x * x;
    }
    __shared__ float rs[32][8], rq[32][8], stat[2][8];
    rs[grp][sg] = sum; rq[grp][sg] = ssq;
    __syncthreads();
    for (int h = 16; h >= 1; h >>= 1) {
        if (grp < h) { rs[grp][sg] += rs[grp + h][sg]; rq[grp][sg] += rq[grp + h][sg]; }
        __syncthreads();
    }
    if (grp == 0) {
        float S1 = rs[0][sg], S2 = rq[0][sg];
        float mean = S1 * (1.0f / 1024.0f);
        float ssc = fmaxf(S2 - 1024.0f * mean * mean, 0.0f);
        stat[0][sg] = mean;
        stat[1][sg] = 1.0f / (sqrtf(ssc) * (1.0f / 32.0f) + 1e-5f);
    }
    __syncthreads();
    float mean = stat[0][sg], inv = stat[1][sg];
    size_t tbase = (((size_t)b << 10) + s) * 1024 + grp * 32;
    #pragma unroll
    for (int j0 = 0; j0 < 32; j0 += 4) {
        unsigned short uh[4], ul[4];
        #pragma unroll
        for (int jj = 0; jj < 4; ++jj) {
            float o = (v[j0 + jj] - mean) * inv;
            o = (o >= 0.f) ? o : 0.02f * o;
            uh[jj] = f2bf(o);
            ul[jj] = f2bf(o - bf2f(uh[jj]));
        }
        *(ushort4*)(oh + tbase + j0) = (ushort4){uh[0], uh[1], uh[2], uh[3]};
        *(ushort4*)(ol + tbase + j0) = (ushort4){ul[0], ul[1], ul[2], ul[3]};
    }
}

// ------- normgate: gated combine + norm + leaky + gate2 (logits/softmax/argmax) ------
// in h1 fp32 [B,3072,S]: v = a*m2+d2; out gT2 bf16 [b][s][i]; idx2; acc[8..15]
__global__ __launch_bounds__(256) void normgate_kernel(
    const float* __restrict__ h1, const float* __restrict__ wg,
    unsigned short* __restrict__ outT, int* __restrict__ idx, float* __restrict__ acc)
{
    int blk = blockIdx.x;
    int b = blk >> 7;
    int s0 = (blk & 127) * 8;
    int tid = threadIdx.x;
    int sg = tid & 7, grp = tid >> 3;
    int s = s0 + sg;
    const float* bp = h1 + ((size_t)b * 3072) * SDIM + s;
    float v[32];
    float sum = 0.f, ssq = 0.f;
    #pragma unroll
    for (int j = 0; j < 32; ++j) {
        int i = grp * 32 + j;
        float a  = bp[(size_t)i * SDIM];
        float m2 = bp[(size_t)(1024 + i) * SDIM];
        float d2 = bp[(size_t)(2048 + i) * SDIM];
        float x = a * m2 + d2;
        v[j] = x; sum += x; ssq += x * x;
    }
    __shared__ float rs[32][8], rq[32][8], stat[2][8];
    rs[grp][sg] = sum; rq[grp][sg] = ssq;
    __syncthreads();
    for (int h = 16; h >= 1; h >>= 1) {
        if (grp < h) { rs[grp][sg] += rs[grp + h][sg]; rq[grp][sg] += rq[grp + h][sg]; }
        __syncthreads();
    }
    if (grp == 0) {
        float S1 = rs[0][sg], S2 = rq[0][sg];
        float mean = S1 * (1.0f / 1024.0f);
        float ssc = fmaxf(S2 - 1024.0f * mean * mean, 0.0f);
        stat[0][sg] = mean;
        stat[1][sg] = 1.0f / (sqrtf(ssc) * (1.0f / 32.0f) + 1e-5f);
    }
    __syncthreads();
    float mean = stat[0][sg], inv = stat[1][sg];
    float l0 = 0.f, l1 = 0.f, l2 = 0.f, l3 = 0.f;
    size_t tbase = (((size_t)b << 10) + s) * 1024 + grp * 32;
    #pragma unroll
    for (int j0 = 0; j0 < 32; j0 += 4) {
        unsigned short u[4];
        #pragma unroll
        for (int jj = 0; jj < 4; ++jj) {
            int i = grp * 32 + j0 + jj;
            float o = (v[j0 + jj] - mean) * inv;
            o = (o >= 0.f) ? o : 0.02f * o;
            u[jj] = f2bf(o);
            l0 += o * wg[i];
            l1 += o * wg[1024 + i];
            l2 += o * wg[2048 + i];
            l3 += o * wg[3072 + i];
        }
        *(ushort4*)(outT + tbase + j0) = (ushort4){u[0], u[1], u[2], u[3]};
    }
    __shared__ float pl[4][32][8];
    __shared__ float la[8];
    pl[0][grp][sg] = l0; pl[1][grp][sg] = l1;
    pl[2][grp][sg] = l2; pl[3][grp][sg] = l3;
    if (tid < 8) la[tid] = 0.f;
    __syncthreads();
    for (int h = 16; h >= 1; h >>= 1) {
        if (grp < h) {
            #pragma unroll
            for (int e = 0; e < 4; ++e) pl[e][grp][sg] += pl[e][grp + h][sg];
        }
        __syncthreads();
    }
    if (grp == 0) {
        float L[4] = {pl[0][0][sg], pl[1][0][sg], pl[2][0][sg], pl[3][0][sg]};
        float m = fmaxf(fmaxf(L[0], L[1]), fmaxf(L[2], L[3]));
        float e0 = expf(L[0] - m), e1 = expf(L[1] - m), e2 = expf(L[2] - m), e3 = expf(L[3] - m);
        float invs = 1.0f / (e0 + e1 + e2 + e3);
        int best = 0; float bv = L[0];
        if (L[1] > bv) { bv = L[1]; best = 1; }
        if (L[2] > bv) { bv = L[2]; best = 2; }
        if (L[3] > bv) { bv = L[3]; best = 3; }
        idx[(b << 10) + s] = best;
        atomicAdd(&la[0], e0 * invs);
        atomicAdd(&la[1], e1 * invs);
        atomicAdd(&la[2], e2 * invs);
        atomicAdd(&la[3], e3 * invs);
        atomicAdd(&la[4 + best], 1.0f);
    }
    __syncthreads();
    if (tid < 8) atomicAdd(&acc[8 + tid], la[tid]);
}

// ---------------- final loss ----------------
__global__ void loss_kernel(const float* __restrict__ acc, float* __restrict__ out) {
    if (threadIdx.x == 0) {
        float l = 0.f;
        for (int e = 0; e < 4; ++e)
            l += acc[e] * acc[4 + e] + acc[8 + e] * acc[12 + e];
        out[2 * 512 * 1024] = l * (1.0f / (2048.0f * 2048.0f));
    }
}

extern "C" void kernel_launch(void* const* d_in, const int* in_sizes, int n_in,
                              void* d_out, int out_size, void* d_ws, size_t ws_size,
                              hipStream_t stream) {
    const float* inp     = (const float*)d_in[0];
    const float* divisor = (const float*)d_in[1];
    const float* w0_gate = (const float*)d_in[2];
    const float* w0      = (const float*)d_in[3];
    const float* w1      = (const float*)d_in[4];
    const float* w2_gate = (const float*)d_in[5];
    const float* w2      = (const float*)d_in[6];
    float* out = (float*)d_out;
    (void)in_sizes; (void)n_in; (void)out_size; (void)ws_size;

    char* ws = (char*)d_ws;
    const unsigned short* base = (const unsigned short*)ws;

    float* h1            = (float*)(ws + 0);                  // 25165824
    float* g             = (float*)(ws + 25165824);           //  8388608
    unsigned short* gT1h = (unsigned short*)(ws + 33554432);  //  4194304
    unsigned short* gT1l = (unsigned short*)(ws + 37748736);  //  4194304
    unsigned short* w1Th = (unsigned short*)(ws + 41943040);  // 18874368
    unsigned short* w1Tl = (unsigned short*)(ws + 60817408);  // 18874368
    unsigned short* xTh  = (unsigned short*)(ws + 79691776);  //  2097152
    unsigned short* xTl  = (unsigned short*)(ws + 81788928);  //  2097152
    unsigned short* w0Th = (unsigned short*)(ws + 83886080);  // 12582912
    unsigned short* w0Tl = (unsigned short*)(ws + 96468992);  // 12582912
    unsigned short* gT2  = (unsigned short*)(ws + 79691776);  //  4194304 (reuse)
    unsigned short* w2T  = (unsigned short*)(ws + 83886080);  //  4194304 (reuse)
    int* idx1            = (int*)(ws + 109051904);
    int* idx2            = (int*)(ws + 109060096);
    float* acc           = (float*)(ws + 109068288);

    const unsigned int GT1H = 16777216u, GT1L = 18874368u;
    const unsigned int W1TH = 20971520u, W1TL = 30408704u;
    const unsigned int XTH  = 39845888u, XTL  = 40894464u;
    const unsigned int W0TH = 41943040u, W0TL = 48234496u;

    init_acc_kernel<<<1, 16, 0, stream>>>(acc);

    transpose_cvt_split<<<dim3(32, 16, 2), 256, 0, stream>>>(inp, xTh, xTl, 512, 1024, (size_t)512 * 1024);
    transpose_cvt_split<<<dim3(96, 16, 4), 256, 0, stream>>>(w0, w0Th, w0Tl, 512, 3072, (size_t)512 * 3072);
    w1cvt_split_kernel<<<12288, 256, 0, stream>>>(w1, w1Th, w1Tl);

    // MoE 1 (split, fp32-accurate): 48 d-tiles x 16 token-tiles
    gate_kernel<<<64, 256, 0, stream>>>(inp, w0_gate, idx1, acc, 512, 0);
    moe_split_kernel<<<768, 256, 0, stream>>>(base, XTH, XTL, W0TH, W0TL, idx1, h1, 512, 3072, 48);

    // w2 -> w2T (plain bf16); after MoE1 (overlaps w0Th region)
    transpose_cvt<<<dim3(16, 32, 4), 256, 0, stream>>>(w2, w2T, 1024, 512, (size_t)1024 * 512);

    cumsum_affine_kernel<<<2048, 256, 0, stream>>>(h1, divisor, g);
    norm0_kernel<<<256, 256, 0, stream>>>(g, gT1h, gT1l);
    // conv (split): 48 o-tiles x 16 token-tiles
    conv_split_kernel<<<768, 256, 0, stream>>>(base, GT1H, GT1L, W1TH, W1TL, h1);
    // fused gated-combine + norm + leaky + gate2
    normgate_kernel<<<256, 256, 0, stream>>>(h1, w2_gate, gT2, idx2, acc);

    // MoE 2 (plain bf16): 8 d-tiles x 16 token-tiles
    moe_kernel<<<128, 256, 0, stream>>>(gT2, w2T, idx2, out, 1024, 512, 8);
    loss_kernel<<<1, 64, 0, stream>>>(acc, out);
}